// Round 2
// 283.008 us; speedup vs baseline: 1.0464x; 1.0464x over previous
//
#include <hip/hip_runtime.h>

// YOLO layer: (64, 3*10, 152, 152) fp32 -> (64, 3*152*152, 10) fp32
// channel-planar -> channel-interleaved with sigmoid/exp/affine decode.
// Memory-bound: ~177 MB in + ~177 MB out. Fill kernels on this chip hit
// 6.5 TB/s => kernel floor ~56-65 us.
//
// v2b: 4 cells/thread => all input reads are float4 (16 B/lane, the measured
// BW sweet spot); channel-major LDS transpose (stride 516 => bank =
// (4*ch + cell) % 32, <=2-way conflicts ~ free); nontemporal load/store
// (streams >> L2, no reuse) via native clang vector type (HIP_vector_type
// structs are rejected by the builtin); 4x fewer waves than v1.

#define NA 3
#define NC 3
#define GSZ 152
#define GG (GSZ * GSZ)        // 23104
#define CH 10                 // 7 + NC
#define BATCH 64
#define BLOCK 128
#define CPT 4                 // cells per thread (float4 granularity)
#define NCELL (BLOCK * CPT)   // 512 cells per block
#define LDS_S 516             // LDS row stride in floats; 516 % 32 == 4
#define LDSF (CH * LDS_S)     // 5160 floats = 20640 B -> 7 blocks/CU

typedef float f32x4 __attribute__((ext_vector_type(4)));

__global__ __launch_bounds__(BLOCK) void yolo_decode_kernel(
    const float* __restrict__ x,
    const int* __restrict__ img_size_p,
    float* __restrict__ out)
{
    __shared__ float lds[LDSF];

    const int tid = threadIdx.x;
    // GG % 4 == 0 and GSZ % 4 == 0 => a thread's 4 cells never straddle a
    // plane boundary or a grid row.
    const int cell_g0 = blockIdx.x * NCELL + tid * CPT;

    const int plane = cell_g0 / GG;                 // b*NA + a
    const int cell0 = cell_g0 - plane * GG;
    const int a   = plane % NA;
    const int gy  = cell0 / GSZ;
    const int gx0 = cell0 - gy * GSZ;

    // img_size scalar: expected int32, but hedge against fp32 encoding.
    const int   iv = img_size_p[0];
    const float fv = __int_as_float(iv);
    const float img = (iv > 0 && iv < 100000) ? (float)iv : fv;
    const float stride = img / (float)GSZ;          // 4.0 for 608/152

    // selects, not runtime array indexing (avoid scratch)
    const float awa = (a == 0) ? 11.0f : (a == 1) ? 24.0f : 42.0f;
    const float aha = (a == 0) ? 14.0f : (a == 1) ? 17.0f : 27.0f;

    // ---- coalesced float4 planar reads: 10 loads, 16 B/lane ----
    const int base = plane * (CH * GG) + cell0;     // fits int32, 16B-aligned
    f32x4 v4[CH];
    #pragma unroll
    for (int c = 0; c < CH; ++c)
        v4[c] = __builtin_nontemporal_load(
            (const f32x4*)(x + base + c * GG));
    float* v = (float*)v4;                          // v[c*4 + i]

    // ---- decode 4 cells ----
    f32x4 o4[CH];
    float* o = (float*)o4;
    const float gyf = (float)gy;
    #pragma unroll
    for (int i = 0; i < CPT; ++i) {
        const float gxf = (float)(gx0 + i);
        o[0*4+i] = (1.0f / (1.0f + __expf(-v[0*4+i])) + gxf) * stride;  // bx
        o[1*4+i] = (1.0f / (1.0f + __expf(-v[1*4+i])) + gyf) * stride;  // by
        o[2*4+i] = (__expf(v[2*4+i]) * (awa / stride)) * stride;        // bw
        o[3*4+i] = (__expf(v[3*4+i]) * (aha / stride)) * stride;        // bh
        o[4*4+i] = v[4*4+i];                                            // im
        o[5*4+i] = v[5*4+i];                                            // re
        o[6*4+i] = 1.0f / (1.0f + __expf(-v[6*4+i]));                   // conf
        o[7*4+i] = 1.0f / (1.0f + __expf(-v[7*4+i]));                   // cls0
        o[8*4+i] = 1.0f / (1.0f + __expf(-v[8*4+i]));                   // cls1
        o[9*4+i] = 1.0f / (1.0f + __expf(-v[9*4+i]));                   // cls2
    }

    // ---- channel-major LDS stage: lds[c][cell], contiguous b128 writes ----
    #pragma unroll
    for (int c = 0; c < CH; ++c)
        *(f32x4*)&lds[c * LDS_S + tid * CPT] = o4[c];
    __syncthreads();

    // ---- contiguous float4 stores of the block's 20 KB output region ----
    // out float j (within block) = cell j/10, ch j%10 -> lds[(j%10)*S + j/10]
    f32x4* outv = (f32x4*)(out + (long long)blockIdx.x * (NCELL * CH));
    #pragma unroll
    for (int it = 0; it < CH; ++it) {               // 1280 float4 / 128 thr
        const int idx = it * BLOCK + tid;
        const int j = idx * 4;
        f32x4 w;
        w.x = lds[((j    ) % CH) * LDS_S + ((j    ) / CH)];
        w.y = lds[((j + 1) % CH) * LDS_S + ((j + 1) / CH)];
        w.z = lds[((j + 2) % CH) * LDS_S + ((j + 2) / CH)];
        w.w = lds[((j + 3) % CH) * LDS_S + ((j + 3) / CH)];
        __builtin_nontemporal_store(w, outv + idx);
    }
}

extern "C" void kernel_launch(void* const* d_in, const int* in_sizes, int n_in,
                              void* d_out, int out_size, void* d_ws, size_t ws_size,
                              hipStream_t stream)
{
    const float* x = (const float*)d_in[0];
    const int* img_size = (const int*)d_in[1];
    float* out = (float*)d_out;

    const long long total_cells = (long long)BATCH * NA * GG;  // 4,435,968
    const int grid = (int)(total_cells / NCELL);               // 8664 exact

    yolo_decode_kernel<<<grid, BLOCK, 0, stream>>>(x, img_size, out);
}

// Round 3
// 280.125 us; speedup vs baseline: 1.0571x; 1.0103x over previous
//
#include <hip/hip_runtime.h>

// YOLO layer: (64, 3*10, 152, 152) fp32 -> (64, 3*152*152, 10) fp32
// channel-planar -> channel-interleaved with sigmoid/exp/affine decode.
// Memory-bound: ~177 MB in + ~177 MB out. Copy ceiling ~6.3 TB/s =>
// kernel floor ~56-59 us (fills in this harness sustain 6.5 TB/s).
//
// v3: BLOCK=256 x CPT=2 (was 128x4). Same 512 cells/block, same 20.6 KB
// LDS, same grid -- but 7 blocks/CU x 4 waves = 28 waves/CU (was 14).
// Streaming kernel with phase-serial blocks needs the extra TLP to keep
// read+write streams saturated. Loads are dwordx2 (8 B/lane, still in
// the coalescing sweet spot); LDS writes ds_write_b64 (2-way = free).

#define NA 3
#define NC 3
#define GSZ 152
#define GG (GSZ * GSZ)        // 23104
#define CH 10                 // 7 + NC
#define BATCH 64
#define BLOCK 256
#define CPT 2                 // cells per thread
#define NCELL (BLOCK * CPT)   // 512 cells per block
#define LDS_S 516             // LDS row stride in floats; 516 % 32 == 4
#define LDSF (CH * LDS_S)     // 5160 floats = 20640 B -> 7 blocks/CU

typedef float f32x4 __attribute__((ext_vector_type(4)));
typedef float f32x2 __attribute__((ext_vector_type(2)));

__global__ __launch_bounds__(BLOCK) void yolo_decode_kernel(
    const float* __restrict__ x,
    const int* __restrict__ img_size_p,
    float* __restrict__ out)
{
    __shared__ float lds[LDSF];

    const int tid = threadIdx.x;
    // GG % 2 == 0 and GSZ % 2 == 0 => a thread's 2 cells never straddle a
    // plane boundary or a grid row.
    const int cell_g0 = blockIdx.x * NCELL + tid * CPT;

    const int plane = cell_g0 / GG;                 // b*NA + a
    const int cell0 = cell_g0 - plane * GG;
    const int a   = plane % NA;
    const int gy  = cell0 / GSZ;
    const int gx0 = cell0 - gy * GSZ;

    // img_size scalar: expected int32, but hedge against fp32 encoding.
    const int   iv = img_size_p[0];
    const float fv = __int_as_float(iv);
    const float img = (iv > 0 && iv < 100000) ? (float)iv : fv;
    const float stride = img / (float)GSZ;          // 4.0 for 608/152

    // selects, not runtime array indexing (avoid scratch)
    const float awa = (a == 0) ? 11.0f : (a == 1) ? 24.0f : 42.0f;
    const float aha = (a == 0) ? 14.0f : (a == 1) ? 17.0f : 27.0f;

    // ---- coalesced dwordx2 planar reads: 10 loads, 8 B/lane ----
    const int base = plane * (CH * GG) + cell0;     // fits int32, 8B-aligned
    f32x2 v2[CH];
    #pragma unroll
    for (int c = 0; c < CH; ++c)
        v2[c] = __builtin_nontemporal_load(
            (const f32x2*)(x + base + c * GG));
    float* v = (float*)v2;                          // v[c*2 + i]

    // ---- decode 2 cells ----
    f32x2 o2[CH];
    float* o = (float*)o2;
    const float gyf = (float)gy;
    #pragma unroll
    for (int i = 0; i < CPT; ++i) {
        const float gxf = (float)(gx0 + i);
        o[0*2+i] = (1.0f / (1.0f + __expf(-v[0*2+i])) + gxf) * stride;  // bx
        o[1*2+i] = (1.0f / (1.0f + __expf(-v[1*2+i])) + gyf) * stride;  // by
        o[2*2+i] = (__expf(v[2*2+i]) * (awa / stride)) * stride;        // bw
        o[3*2+i] = (__expf(v[3*2+i]) * (aha / stride)) * stride;        // bh
        o[4*2+i] = v[4*2+i];                                            // im
        o[5*2+i] = v[5*2+i];                                            // re
        o[6*2+i] = 1.0f / (1.0f + __expf(-v[6*2+i]));                   // conf
        o[7*2+i] = 1.0f / (1.0f + __expf(-v[7*2+i]));                   // cls0
        o[8*2+i] = 1.0f / (1.0f + __expf(-v[8*2+i]));                   // cls1
        o[9*2+i] = 1.0f / (1.0f + __expf(-v[9*2+i]));                   // cls2
    }

    // ---- channel-major LDS stage: lds[c][cell], ds_write_b64 ----
    // bank = (4c + 2t) % 32: lanes t, t+16 alias 2-way => free.
    #pragma unroll
    for (int c = 0; c < CH; ++c)
        *(f32x2*)&lds[c * LDS_S + tid * CPT] = o2[c];
    __syncthreads();

    // ---- contiguous float4 stores of the block's 20 KB output region ----
    // out float j (within block) = cell j/10, ch j%10 -> lds[(j%10)*S + j/10]
    f32x4* outv = (f32x4*)(out + (long long)blockIdx.x * (NCELL * CH));
    #pragma unroll
    for (int it = 0; it < 5; ++it) {                // 1280 float4 / 256 thr
        const int idx = it * BLOCK + tid;
        const int j = idx * 4;
        f32x4 w;
        w.x = lds[((j    ) % CH) * LDS_S + ((j    ) / CH)];
        w.y = lds[((j + 1) % CH) * LDS_S + ((j + 1) / CH)];
        w.z = lds[((j + 2) % CH) * LDS_S + ((j + 2) / CH)];
        w.w = lds[((j + 3) % CH) * LDS_S + ((j + 3) / CH)];
        __builtin_nontemporal_store(w, outv + idx);
    }
}

extern "C" void kernel_launch(void* const* d_in, const int* in_sizes, int n_in,
                              void* d_out, int out_size, void* d_ws, size_t ws_size,
                              hipStream_t stream)
{
    const float* x = (const float*)d_in[0];
    const int* img_size = (const int*)d_in[1];
    float* out = (float*)d_out;

    const long long total_cells = (long long)BATCH * NA * GG;  // 4,435,968
    const int grid = (int)(total_cells / NCELL);               // 8664 exact

    yolo_decode_kernel<<<grid, BLOCK, 0, stream>>>(x, img_size, out);
}